// Round 3
// baseline (429.333 us; speedup 1.0000x reference)
//
#include <hip/hip_runtime.h>
#include <math.h>

#define NN 2
#define DD 16
#define HH 32
#define WW 32
#define DIN 18
#define HIN 34
#define WIN 34
#define NVOX 32768
#define ROWS 432                 // 324 offset rows + 108 mask rows
#define NPAD (NN*DIN*HIN*WIN)    // 41616 padded voxels
#define XP_FLOATS (NPAD*64)      // 2,663,424

// ws layout (floats):
#define WS_IN_WT   XP_FLOATS            // 4096 f32: in_w transposed [c][j]
#define WS_OUT_WT  (WS_IN_WT + 4096)    // 4096 f32: out_w transposed [c][j]
#define WS_DWT     (WS_OUT_WT + 4096)   // 1728 f32: dw_w transposed [k][c]
#define WS_CMBB    (WS_DWT + 1728)      // 27648 bf16 (13824 f32): heads [r][c]

typedef short  bf16x8 __attribute__((ext_vector_type(8)));
typedef float  f32x4  __attribute__((ext_vector_type(4)));

__device__ __forceinline__ unsigned short f2bf(float x) {
    unsigned u = __builtin_bit_cast(unsigned, x);
    u += 0x7fff + ((u >> 16) & 1);          // round-to-nearest-even
    return (unsigned short)(u >> 16);
}

// ---------------------------------------------------------------------------
// Setup: transposed fp32 weights + bf16 heads weight copy (native [r][c]).
// ---------------------------------------------------------------------------
__global__ __launch_bounds__(256) void setup(
        const float* __restrict__ in_w,  const float* __restrict__ out_w,
        const float* __restrict__ off_w, const float* __restrict__ mask_w,
        const float* __restrict__ dw_w,  float* __restrict__ ws) {
    int t = blockIdx.x * 256 + threadIdx.x;
    int G = gridDim.x * 256;
    for (int i = t; i < 4096; i += G) {
        int c = i >> 6, j = i & 63;
        ws[WS_IN_WT  + i] = in_w [j * 64 + c];
        ws[WS_OUT_WT + i] = out_w[j * 64 + c];
    }
    for (int i = t; i < 1728; i += G) {
        int k = i >> 6, c = i & 63;
        ws[WS_DWT + i] = dw_w[c * 27 + k];
    }
    unsigned short* cmbB = (unsigned short*)(ws + WS_CMBB);
    for (int i = t; i < 324 * 64; i += G) cmbB[i] = f2bf(off_w[i]);
    for (int i = t; i < 108 * 64; i += G) cmbB[324 * 64 + i] = f2bf(mask_w[i]);
}

// ---------------------------------------------------------------------------
// Value projection over the PADDED grid: interior voxels get input @ in_w^T
// + in_b; the 1-voxel border ring gets zeros (replaces the old zero-fill).
// One wave per padded voxel, 4 per block. NPAD/4 = 10404 blocks.
// ---------------------------------------------------------------------------
__global__ __launch_bounds__(256) void value_proj(
        const float* __restrict__ inp,
        const float* __restrict__ ws_ro,
        const float* __restrict__ in_b,
        float* __restrict__ xp) {
    const float* in_wT = ws_ro + WS_IN_WT;
    __shared__ float lx[4][64];
    int u = threadIdx.x >> 6;
    int j = threadIdx.x & 63;
    int pv = blockIdx.x * 4 + u;
    int wp = pv % 34, hp = (pv / 34) % 34, dp = (pv / 1156) % 18, n = pv / 20808;
    bool interior = (wp >= 1 && wp <= 32 && hp >= 1 && hp <= 32 && dp >= 1 && dp <= 16);
    if (interior) {
        int vox = (((n * 16 + (dp - 1)) * 32 + (hp - 1)) * 32) + (wp - 1);
        lx[u][j] = inp[(size_t)vox * 64 + j];
    }
    __syncthreads();
    float r = 0.f;
    if (interior) {
        float acc = in_b[j];
        #pragma unroll 8
        for (int c = 0; c < 64; ++c)
            acc = fmaf(lx[u][c], in_wT[c * 64 + j], acc);
        r = acc;
    }
    xp[(size_t)pv * 64 + j] = r;
}

// ---------------------------------------------------------------------------
// Fused main: conv+LN+GELU -> heads via MFMA -> softmax -> sampling
// (precompute + lean gather) -> out proj. 4 waves = 4 voxels per block.
// ---------------------------------------------------------------------------
__global__ __launch_bounds__(256, 4) void dcn_main(
        const float* __restrict__ inp,
        const float* __restrict__ dw_b,
        const float* __restrict__ ln_g,  const float* __restrict__ ln_b,
        const float* __restrict__ off_b, const float* __restrict__ mask_b,
        const float* __restrict__ ws_ro,
        const float* __restrict__ out_b,
        float* __restrict__ out) {
    const float* xp     = ws_ro;
    const float* out_wT = ws_ro + WS_OUT_WT;
    const float* dwT    = ws_ro + WS_DWT;
    const unsigned short* cmbB = (const unsigned short*)(ws_ro + WS_CMBB);

    __shared__ __align__(16) unsigned short s_a[16 * 64]; // A frag [m][k], m=vox(0..3 live)
    __shared__ float s_om[4 * ROWS];                      // logits: 324 off + 108 mask / vox
    __shared__ __align__(16) float s_pre[432 * 16];       // per item: 8 weights + 8 offsets

    int t = threadIdx.x;
    int u = t >> 6, lane = t & 63;
    int vox = blockIdx.x * 4 + u;
    int w = vox & 31, h = (vox >> 5) & 31, d = (vox >> 10) & 15, n = vox >> 14;

    // zero A-fragment rows 4..15 (so MFMA garbage rows stay clean)
    for (int i = t; i < 384; i += 256) ((unsigned*)s_a)[128 + i] = 0u;

    // ---- Stage 1: depthwise conv + LN + GELU (lane = channel)
    {
        int c = lane;
        float acc = dw_b[c];
        #pragma unroll
        for (int kd = 0; kd < 3; ++kd) {
            int dz = d + kd - 1;
            if ((unsigned)dz >= DD) continue;
            #pragma unroll
            for (int kh = 0; kh < 3; ++kh) {
                int hy = h + kh - 1;
                if ((unsigned)hy >= HH) continue;
                #pragma unroll
                for (int kw = 0; kw < 3; ++kw) {
                    int wx = w + kw - 1;
                    if ((unsigned)wx >= WW) continue;
                    float v = inp[((((size_t)n * DD + dz) * HH + hy) * WW + wx) * 64 + c];
                    acc = fmaf(v, dwT[(kd * 9 + kh * 3 + kw) * 64 + c], acc);
                }
            }
        }
        float s = acc, ss = acc * acc;
        #pragma unroll
        for (int m = 1; m < 64; m <<= 1) {
            s  += __shfl_xor(s,  m, 64);
            ss += __shfl_xor(ss, m, 64);
        }
        float mu  = s * (1.f / 64.f);
        float var = ss * (1.f / 64.f) - mu * mu;
        float x1 = (acc - mu) * rsqrtf(var + 1e-6f) * ln_g[c] + ln_b[c];
        x1 = 0.5f * x1 * (1.f + erff(x1 * 0.70710678118654752f));
        s_a[u * 64 + c] = f2bf(x1);
    }
    __syncthreads();

    // ---- Stage 2: heads (432x64 @ x1) via MFMA 16x16x32 bf16
    // A[m][k]: m=voxel (rows 0..3 live), k=channel. B[k][n]: n = head row.
    {
        int quad = lane >> 4, nid = lane & 15;
        bf16x8 a0 = *(const bf16x8*)&s_a[nid * 64 + quad * 8];
        bf16x8 a1 = *(const bf16x8*)&s_a[nid * 64 + quad * 8 + 32];
        for (int tl = u; tl < 27; tl += 4) {
            int r = tl * 16 + nid;
            bf16x8 b0 = *(const bf16x8*)&cmbB[r * 64 + quad * 8];
            bf16x8 b1 = *(const bf16x8*)&cmbB[r * 64 + quad * 8 + 32];
            f32x4 acc = {0.f, 0.f, 0.f, 0.f};
            acc = __builtin_amdgcn_mfma_f32_16x16x32_bf16(a0, b0, acc, 0, 0, 0);
            acc = __builtin_amdgcn_mfma_f32_16x16x32_bf16(a1, b1, acc, 0, 0, 0);
            if (quad == 0) {   // D rows 0..3 = voxels 0..3 live in lanes 0..15
                float bias = (r < 324) ? off_b[r] : mask_b[r - 324];
                s_om[0 * ROWS + r] = acc[0] + bias;
                s_om[1 * ROWS + r] = acc[1] + bias;
                s_om[2 * ROWS + r] = acc[2] + bias;
                s_om[3 * ROWS + r] = acc[3] + bias;
            }
        }
    }
    __syncthreads();

    // ---- Stage 3: softmax over 27 points per (voxel, group); 8 lanes each
    if (t < 128) {
        int v = t >> 5, g = (t >> 3) & 3, l = t & 7;
        float* m = &s_om[v * ROWS + 324 + g * 27];
        float mx = -1e30f;
        #pragma unroll
        for (int i = 0; i < 4; ++i) { int p = l + 8 * i; if (p < 27) mx = fmaxf(mx, m[p]); }
        mx = fmaxf(mx, __shfl_xor(mx, 1, 64));
        mx = fmaxf(mx, __shfl_xor(mx, 2, 64));
        mx = fmaxf(mx, __shfl_xor(mx, 4, 64));
        float e[4]; float sm = 0.f;
        #pragma unroll
        for (int i = 0; i < 4; ++i) {
            int p = l + 8 * i;
            e[i] = (p < 27) ? expf(m[p] - mx) : 0.f;
            sm += e[i];
        }
        sm += __shfl_xor(sm, 1, 64);
        sm += __shfl_xor(sm, 2, 64);
        sm += __shfl_xor(sm, 4, 64);
        float inv = 1.f / sm;
        #pragma unroll
        for (int i = 0; i < 4; ++i) { int p = l + 8 * i; if (p < 27) m[p] = e[i] * inv; }
    }
    __syncthreads();

    // ---- Stage 4a: per-(vox,grp,point) precompute of 8 weights + 8 offsets
    for (int item = t; item < 432; item += 256) {
        int v = item / 108, rem = item - v * 108;
        int g = rem / 27,   p   = rem - g * 27;
        int ix = p / 9, r9 = p - ix * 9, iy = r9 / 3, iz = r9 - iy * 3;
        const float* om = &s_om[v * ROWS];
        float ox = om[(g * 27 + p) * 3 + 0];
        float oy = om[(g * 27 + p) * 3 + 1];
        float oz = om[(g * 27 + p) * 3 + 2];
        float msk = om[324 + g * 27 + p];
        int vx = blockIdx.x * 4 + v;
        int wv = vx & 31, hv = (vx >> 5) & 31, dv = (vx >> 10) & 15;
        float px = (float)(wv + ix) + ox;
        float py = (float)(hv + iy) + oy;
        float pz = (float)(dv + iz) + oz;
        float fx0 = floorf(px); int x0 = (int)fx0; float fx = px - fx0;
        float fy0 = floorf(py); int y0 = (int)fy0; float fy = py - fy0;
        float fz0 = floorf(pz); int z0 = (int)fz0; float fz = pz - fz0;
        float wx0 = ((unsigned)x0       < WIN) ? (1.f - fx) : 0.f;
        float wx1 = ((unsigned)(x0 + 1) < WIN) ? fx         : 0.f;
        float wy0 = ((unsigned)y0       < HIN) ? (1.f - fy) : 0.f;
        float wy1 = ((unsigned)(y0 + 1) < HIN) ? fy         : 0.f;
        float wz0 = ((unsigned)z0       < DIN) ? (1.f - fz) : 0.f;
        float wz1 = ((unsigned)(z0 + 1) < DIN) ? fz         : 0.f;
        wz0 *= msk; wz1 *= msk;
        int x0c = min(max(x0, 0), WIN - 1), x1c = min(max(x0 + 1, 0), WIN - 1);
        int y0c = min(max(y0, 0), HIN - 1), y1c = min(max(y0 + 1, 0), HIN - 1);
        int z0c = min(max(z0, 0), DIN - 1), z1c = min(max(z0 + 1, 0), DIN - 1);
        int zb0 = z0c * (HIN * WIN), zb1 = z1c * (HIN * WIN);
        int yb0 = y0c * WIN,         yb1 = y1c * WIN;
        float wzy00 = wz0 * wy0, wzy01 = wz0 * wy1, wzy10 = wz1 * wy0, wzy11 = wz1 * wy1;
        float* pr = &s_pre[item * 16];
        pr[0] = wzy00 * wx0; pr[1] = wzy00 * wx1;
        pr[2] = wzy01 * wx0; pr[3] = wzy01 * wx1;
        pr[4] = wzy10 * wx0; pr[5] = wzy10 * wx1;
        pr[6] = wzy11 * wx0; pr[7] = wzy11 * wx1;
        int* pi = (int*)(pr + 8);
        pi[0] = (zb0 + yb0 + x0c) << 6; pi[1] = (zb0 + yb0 + x1c) << 6;
        pi[2] = (zb0 + yb1 + x0c) << 6; pi[3] = (zb0 + yb1 + x1c) << 6;
        pi[4] = (zb1 + yb0 + x0c) << 6; pi[5] = (zb1 + yb0 + x1c) << 6;
        pi[6] = (zb1 + yb1 + x0c) << 6; pi[7] = (zb1 + yb1 + x1c) << 6;
    }
    __syncthreads();

    // ---- Stage 4b: lean gather (lane = channel), then out-proj via shfl
    {
        int g = lane >> 4;
        const float* xpn = xp + (size_t)n * (DIN * HIN * WIN * 64) + lane;
        const float* prebase = &s_pre[(size_t)((u * 4 + g) * 27) * 16];
        float acc = 0.f;
        #pragma unroll 9
        for (int p = 0; p < 27; ++p) {
            float4 wA = *(const float4*)(prebase + p * 16);
            float4 wB = *(const float4*)(prebase + p * 16 + 4);
            int4   oA = *(const int4*)  (prebase + p * 16 + 8);
            int4   oB = *(const int4*)  (prebase + p * 16 + 12);
            acc = fmaf(wA.x, xpn[oA.x], acc);
            acc = fmaf(wA.y, xpn[oA.y], acc);
            acc = fmaf(wA.z, xpn[oA.z], acc);
            acc = fmaf(wA.w, xpn[oA.w], acc);
            acc = fmaf(wB.x, xpn[oB.x], acc);
            acc = fmaf(wB.y, xpn[oB.y], acc);
            acc = fmaf(wB.z, xpn[oB.z], acc);
            acc = fmaf(wB.w, xpn[oB.w], acc);
        }
        float o = out_b[lane];
        #pragma unroll 8
        for (int c = 0; c < 64; ++c) {
            float vc = __shfl(acc, c, 64);
            o = fmaf(vc, out_wT[c * 64 + lane], o);
        }
        out[(size_t)vox * 64 + lane] = o;
    }
}

extern "C" void kernel_launch(void* const* d_in, const int* in_sizes, int n_in,
                              void* d_out, int out_size, void* d_ws, size_t ws_size,
                              hipStream_t stream) {
    const float* inp    = (const float*)d_in[0];
    const float* dw_w   = (const float*)d_in[1];
    const float* dw_b   = (const float*)d_in[2];
    const float* ln_g   = (const float*)d_in[3];
    const float* ln_b   = (const float*)d_in[4];
    const float* off_w  = (const float*)d_in[5];
    const float* off_b  = (const float*)d_in[6];
    const float* mask_w = (const float*)d_in[7];
    const float* mask_b = (const float*)d_in[8];
    const float* in_w   = (const float*)d_in[9];
    const float* in_b   = (const float*)d_in[10];
    const float* out_w  = (const float*)d_in[11];
    const float* out_b  = (const float*)d_in[12];

    float* ws = (float*)d_ws;

    setup<<<64, 256, 0, stream>>>(in_w, out_w, off_w, mask_w, dw_w, ws);
    value_proj<<<NPAD / 4, 256, 0, stream>>>(inp, ws, in_b, ws);
    dcn_main<<<NVOX / 4, 256, 0, stream>>>(inp, dw_b, ln_g, ln_b,
                                           off_b, mask_b, ws, out_b,
                                           (float*)d_out);
}

// Round 4
// 225.199 us; speedup vs baseline: 1.9065x; 1.9065x over previous
//
#include <hip/hip_runtime.h>
#include <math.h>

#define NN 2
#define DD 16
#define HH 32
#define WW 32
#define DIN 18
#define HIN 34
#define WIN 34
#define NVOX 32768
#define ROWS 432                 // 324 offset rows + 108 mask rows
#define NPAD (NN*DIN*HIN*WIN)    // 41616 padded voxels
#define XP_FLOATS (NPAD*64)      // 2,663,424
#define SOMSTR 436               // padded stride for s_om (bank-conflict-free quads)

// ws layout (float offsets):
#define WS_IN_WT   XP_FLOATS            // 4096 f32: in_w transposed [c][j]
#define WS_DWT     (WS_IN_WT + 4096)    // 1728 f32: dw_w transposed [k][c]
#define WS_CMBB    (WS_DWT + 1728)      // 27648 bf16: heads weights native [r][c]
#define WS_OUTB    (WS_CMBB + 13824)    // 4096 bf16: out_w native [j][c]

typedef short  bf16x8 __attribute__((ext_vector_type(8)));
typedef float  f32x4  __attribute__((ext_vector_type(4)));

__device__ __forceinline__ unsigned short f2bf(float x) {
    unsigned u = __builtin_bit_cast(unsigned, x);
    u += 0x7fff + ((u >> 16) & 1);          // round-to-nearest-even
    return (unsigned short)(u >> 16);
}

// ---------------------------------------------------------------------------
__global__ __launch_bounds__(256) void setup(
        const float* __restrict__ in_w,  const float* __restrict__ out_w,
        const float* __restrict__ off_w, const float* __restrict__ mask_w,
        const float* __restrict__ dw_w,  float* __restrict__ ws) {
    int t = blockIdx.x * 256 + threadIdx.x;
    int G = gridDim.x * 256;
    for (int i = t; i < 4096; i += G) {
        int c = i >> 6, j = i & 63;
        ws[WS_IN_WT + i] = in_w[j * 64 + c];
    }
    for (int i = t; i < 1728; i += G) {
        int k = i >> 6, c = i & 63;
        ws[WS_DWT + i] = dw_w[c * 27 + k];
    }
    unsigned short* cmbB = (unsigned short*)(ws + WS_CMBB);
    for (int i = t; i < 324 * 64; i += G) cmbB[i] = f2bf(off_w[i]);
    for (int i = t; i < 108 * 64; i += G) cmbB[324 * 64 + i] = f2bf(mask_w[i]);
    unsigned short* outB = (unsigned short*)(ws + WS_OUTB);
    for (int i = t; i < 4096; i += G) outB[i] = f2bf(out_w[i]);
}

// ---------------------------------------------------------------------------
// Value projection over the PADDED grid; border ring written as zeros.
// ---------------------------------------------------------------------------
__global__ __launch_bounds__(256) void value_proj(
        const float* __restrict__ inp,
        const float* __restrict__ ws_ro,
        const float* __restrict__ in_b,
        float* __restrict__ xp) {
    const float* in_wT = ws_ro + WS_IN_WT;
    __shared__ float lx[4][64];
    int u = threadIdx.x >> 6;
    int j = threadIdx.x & 63;
    int pv = blockIdx.x * 4 + u;
    int wp = pv % 34, hp = (pv / 34) % 34, dp = (pv / 1156) % 18, n = pv / 20808;
    bool interior = (wp >= 1 && wp <= 32 && hp >= 1 && hp <= 32 && dp >= 1 && dp <= 16);
    if (interior) {
        int vox = (((n * 16 + (dp - 1)) * 32 + (hp - 1)) * 32) + (wp - 1);
        lx[u][j] = inp[(size_t)vox * 64 + j];
    }
    __syncthreads();
    float r = 0.f;
    if (interior) {
        float acc = in_b[j];
        #pragma unroll 8
        for (int c = 0; c < 64; ++c)
            acc = fmaf(lx[u][c], in_wT[c * 64 + j], acc);
        r = acc;
    }
    xp[(size_t)pv * 64 + j] = r;
}

// ---------------------------------------------------------------------------
// Fused main, 16 voxels / block (4 waves).
//  S1 conv+LN+GELU (wave u -> voxels 4u..4u+3, lane=channel)
//  S2 heads MFMA, full 16-row A
//  S3 softmax (quad per (vox,group))
//  S4 gather: wave u = group u, lane = (vox=lane>>2, chquad=lane&3), float4
//  S5 out-projection MFMA (bf16)
// ---------------------------------------------------------------------------
__global__ __launch_bounds__(256, 4) void dcn_main(
        const float* __restrict__ inp,
        const float* __restrict__ dw_b,
        const float* __restrict__ ln_g,  const float* __restrict__ ln_b,
        const float* __restrict__ off_b, const float* __restrict__ mask_b,
        const float* __restrict__ ws_ro,
        const float* __restrict__ out_b,
        float* __restrict__ out) {
    const float* xp   = ws_ro;
    const float* dwT  = ws_ro + WS_DWT;
    const unsigned short* cmbB = (const unsigned short*)(ws_ro + WS_CMBB);
    const unsigned short* outB = (const unsigned short*)(ws_ro + WS_OUTB);

    __shared__ __align__(16) unsigned short s_a[16 * 64];   // x1 bf16 [vox][ch]
    __shared__ float s_om[16 * SOMSTR];                     // [vox][432] logits
    __shared__ __align__(16) unsigned short s_vb[16 * 64];  // sampled vals bf16

    int t = threadIdx.x;
    int u = t >> 6, lane = t & 63;
    int nid = lane & 15, quad = lane >> 4;
    int vox0 = blockIdx.x * 16;
    int w0 = vox0 & 31;                 // 0 or 16; voxel vb has w = w0 + vb
    int h0 = (vox0 >> 5) & 31;
    int d0 = (vox0 >> 10) & 15;
    int n  = vox0 >> 14;

    // ---- S1: depthwise conv + LN + GELU
    {
        int c = lane;
        #pragma unroll
        for (int i = 0; i < 4; ++i) {
            int vb = u * 4 + i;
            int wv = w0 + vb;
            float acc = dw_b[c];
            #pragma unroll
            for (int kd = 0; kd < 3; ++kd) {
                int dz = d0 + kd - 1;
                if ((unsigned)dz >= DD) continue;
                #pragma unroll
                for (int kh = 0; kh < 3; ++kh) {
                    int hy = h0 + kh - 1;
                    if ((unsigned)hy >= HH) continue;
                    #pragma unroll
                    for (int kw = 0; kw < 3; ++kw) {
                        int wx = wv + kw - 1;
                        if ((unsigned)wx >= WW) continue;
                        float v = inp[((((size_t)n * DD + dz) * HH + hy) * WW + wx) * 64 + c];
                        acc = fmaf(v, dwT[(kd * 9 + kh * 3 + kw) * 64 + c], acc);
                    }
                }
            }
            float s = acc, ss = acc * acc;
            #pragma unroll
            for (int m = 1; m < 64; m <<= 1) {
                s  += __shfl_xor(s,  m, 64);
                ss += __shfl_xor(ss, m, 64);
            }
            float mu  = s * (1.f / 64.f);
            float var = ss * (1.f / 64.f) - mu * mu;
            float x1 = (acc - mu) * rsqrtf(var + 1e-6f) * ln_g[c] + ln_b[c];
            x1 = 0.5f * x1 * (1.f + erff(x1 * 0.70710678118654752f));
            s_a[vb * 64 + c] = f2bf(x1);
        }
    }
    __syncthreads();

    // ---- S2: heads (432 rows) via MFMA 16x16x32 bf16, 16 live A rows
    {
        bf16x8 a0 = *(const bf16x8*)&s_a[nid * 64 + quad * 8];
        bf16x8 a1 = *(const bf16x8*)&s_a[nid * 64 + quad * 8 + 32];
        for (int tl = u; tl < 27; tl += 4) {
            int r = tl * 16 + nid;
            bf16x8 b0 = *(const bf16x8*)&cmbB[r * 64 + quad * 8];
            bf16x8 b1 = *(const bf16x8*)&cmbB[r * 64 + quad * 8 + 32];
            f32x4 acc = {0.f, 0.f, 0.f, 0.f};
            acc = __builtin_amdgcn_mfma_f32_16x16x32_bf16(a0, b0, acc, 0, 0, 0);
            acc = __builtin_amdgcn_mfma_f32_16x16x32_bf16(a1, b1, acc, 0, 0, 0);
            float bias = (r < 324) ? off_b[r] : mask_b[r - 324];
            #pragma unroll
            for (int k = 0; k < 4; ++k)
                s_om[(quad * 4 + k) * SOMSTR + r] = acc[k] + bias;   // row=vox, col=r
        }
    }
    __syncthreads();

    // ---- S3: softmax; quad (4 threads) per (vox, group) pair
    {
        int pair = t >> 2, l = t & 3;      // 64 pairs
        int vb = pair >> 2, g = pair & 3;
        float* m = &s_om[vb * SOMSTR + 324 + g * 27];
        float e[7];
        float mx = -1e30f;
        #pragma unroll
        for (int j = 0; j < 7; ++j) {
            int p = l + 4 * j;
            float v = (p < 27) ? m[p] : -1e30f;
            e[j] = v;
            mx = fmaxf(mx, v);
        }
        mx = fmaxf(mx, __shfl_xor(mx, 1, 64));
        mx = fmaxf(mx, __shfl_xor(mx, 2, 64));
        float sm = 0.f;
        #pragma unroll
        for (int j = 0; j < 7; ++j) {
            int p = l + 4 * j;
            e[j] = (p < 27) ? expf(e[j] - mx) : 0.f;
            sm += e[j];
        }
        sm += __shfl_xor(sm, 1, 64);
        sm += __shfl_xor(sm, 2, 64);
        float inv = 1.f / sm;
        #pragma unroll
        for (int j = 0; j < 7; ++j) {
            int p = l + 4 * j;
            if (p < 27) m[p] = e[j] * inv;
        }
    }
    __syncthreads();

    // ---- S4: gather. wave u = group u; lane: vox vb=lane>>2, chquad cq=lane&3
    {
        int vb = lane >> 2, cq = lane & 3;
        int wv = w0 + vb;
        const float* om  = &s_om[vb * SOMSTR];
        const float* xpn = xp + (size_t)n * (DIN * HIN * WIN * 64) + u * 16 + cq * 4;
        float4 acc = make_float4(0.f, 0.f, 0.f, 0.f);
        int p = 0;
        #pragma unroll
        for (int ix = 0; ix < 3; ++ix)
        #pragma unroll
        for (int iy = 0; iy < 3; ++iy)
        #pragma unroll
        for (int iz = 0; iz < 3; ++iz, ++p) {
            int rb = (u * 27 + p) * 3;
            float ox = om[rb + 0], oy = om[rb + 1], oz = om[rb + 2];
            float msk = om[324 + u * 27 + p];
            float px = (float)(wv + ix) + ox;
            float py = (float)(h0 + iy) + oy;
            float pz = (float)(d0 + iz) + oz;
            float fx0 = floorf(px); int x0 = (int)fx0; float fx = px - fx0;
            float fy0 = floorf(py); int y0 = (int)fy0; float fy = py - fy0;
            float fz0 = floorf(pz); int z0 = (int)fz0; float fz = pz - fz0;
            float wx0 = ((unsigned)x0       < WIN) ? (1.f - fx) : 0.f;
            float wx1 = ((unsigned)(x0 + 1) < WIN) ? fx         : 0.f;
            float wy0 = ((unsigned)y0       < HIN) ? (1.f - fy) : 0.f;
            float wy1 = ((unsigned)(y0 + 1) < HIN) ? fy         : 0.f;
            float wz0 = ((unsigned)z0       < DIN) ? (1.f - fz) : 0.f;
            float wz1 = ((unsigned)(z0 + 1) < DIN) ? fz         : 0.f;
            wz0 *= msk; wz1 *= msk;
            int x0c = min(max(x0, 0), WIN - 1), x1c = min(max(x0 + 1, 0), WIN - 1);
            int y0c = min(max(y0, 0), HIN - 1), y1c = min(max(y0 + 1, 0), HIN - 1);
            int z0c = min(max(z0, 0), DIN - 1), z1c = min(max(z0 + 1, 0), DIN - 1);
            int zb0 = z0c * (HIN * WIN), zb1 = z1c * (HIN * WIN);
            int yb0 = y0c * WIN,         yb1 = y1c * WIN;
            int r00 = (zb0 + yb0) << 6, r01 = (zb0 + yb1) << 6;
            int r10 = (zb1 + yb0) << 6, r11 = (zb1 + yb1) << 6;
            int xs0 = x0c << 6, xs1 = x1c << 6;
            float4 v000 = *(const float4*)(xpn + r00 + xs0);
            float4 v001 = *(const float4*)(xpn + r00 + xs1);
            float4 v010 = *(const float4*)(xpn + r01 + xs0);
            float4 v011 = *(const float4*)(xpn + r01 + xs1);
            float4 v100 = *(const float4*)(xpn + r10 + xs0);
            float4 v101 = *(const float4*)(xpn + r10 + xs1);
            float4 v110 = *(const float4*)(xpn + r11 + xs0);
            float4 v111 = *(const float4*)(xpn + r11 + xs1);
            float wzy00 = wz0 * wy0, wzy01 = wz0 * wy1;
            float wzy10 = wz1 * wy0, wzy11 = wz1 * wy1;
            float w000 = wzy00 * wx0, w001 = wzy00 * wx1;
            float w010 = wzy01 * wx0, w011 = wzy01 * wx1;
            float w100 = wzy10 * wx0, w101 = wzy10 * wx1;
            float w110 = wzy11 * wx0, w111 = wzy11 * wx1;
            #define TAP(W, V) \
                acc.x = fmaf(W, V.x, acc.x); acc.y = fmaf(W, V.y, acc.y); \
                acc.z = fmaf(W, V.z, acc.z); acc.w = fmaf(W, V.w, acc.w);
            TAP(w000, v000) TAP(w001, v001) TAP(w010, v010) TAP(w011, v011)
            TAP(w100, v100) TAP(w101, v101) TAP(w110, v110) TAP(w111, v111)
            #undef TAP
        }
        unsigned lo = (unsigned)f2bf(acc.x) | ((unsigned)f2bf(acc.y) << 16);
        unsigned hi = (unsigned)f2bf(acc.z) | ((unsigned)f2bf(acc.w) << 16);
        *(uint2*)&s_vb[vb * 64 + u * 16 + cq * 4] = make_uint2(lo, hi);
    }
    __syncthreads();

    // ---- S5: output projection via MFMA; wave u -> out channels 16u..16u+15
    {
        bf16x8 a0 = *(const bf16x8*)&s_vb[nid * 64 + quad * 8];
        bf16x8 a1 = *(const bf16x8*)&s_vb[nid * 64 + quad * 8 + 32];
        bf16x8 b0 = *(const bf16x8*)&outB[(u * 16 + nid) * 64 + quad * 8];
        bf16x8 b1 = *(const bf16x8*)&outB[(u * 16 + nid) * 64 + quad * 8 + 32];
        f32x4 acc = {0.f, 0.f, 0.f, 0.f};
        acc = __builtin_amdgcn_mfma_f32_16x16x32_bf16(a0, b0, acc, 0, 0, 0);
        acc = __builtin_amdgcn_mfma_f32_16x16x32_bf16(a1, b1, acc, 0, 0, 0);
        float ob = out_b[u * 16 + nid];
        #pragma unroll
        for (int k = 0; k < 4; ++k)
            out[(size_t)(vox0 + quad * 4 + k) * 64 + u * 16 + nid] = acc[k] + ob;
    }
}

extern "C" void kernel_launch(void* const* d_in, const int* in_sizes, int n_in,
                              void* d_out, int out_size, void* d_ws, size_t ws_size,
                              hipStream_t stream) {
    const float* inp    = (const float*)d_in[0];
    const float* dw_w   = (const float*)d_in[1];
    const float* dw_b   = (const float*)d_in[2];
    const float* ln_g   = (const float*)d_in[3];
    const float* ln_b   = (const float*)d_in[4];
    const float* off_w  = (const float*)d_in[5];
    const float* off_b  = (const float*)d_in[6];
    const float* mask_w = (const float*)d_in[7];
    const float* mask_b = (const float*)d_in[8];
    const float* in_w   = (const float*)d_in[9];
    const float* in_b   = (const float*)d_in[10];
    const float* out_w  = (const float*)d_in[11];
    const float* out_b  = (const float*)d_in[12];

    float* ws = (float*)d_ws;

    setup<<<64, 256, 0, stream>>>(in_w, out_w, off_w, mask_w, dw_w, ws);
    value_proj<<<NPAD / 4, 256, 0, stream>>>(inp, ws, in_b, ws);
    dcn_main<<<NVOX / 16, 256, 0, stream>>>(inp, dw_b, ln_g, ln_b,
                                            off_b, mask_b, ws, out_b,
                                            (float*)d_out);
}

// Round 5
// 210.332 us; speedup vs baseline: 2.0412x; 1.0707x over previous
//
#include <hip/hip_runtime.h>
#include <math.h>

#define NN 2
#define DD 16
#define HH 32
#define WW 32
#define DIN 18
#define HIN 34
#define WIN 34
#define NVOX 32768
#define ROWS 432                 // 324 offset rows + 108 mask rows
#define NPAD (NN*DIN*HIN*WIN)    // 41616 padded voxels
#define XP_FLOATS (NPAD*64)      // 2,663,424
#define SOMSTR 436               // s_om stride (bf16 elems), conflict-free

// ws layout (float offsets):
#define WS_DWT    XP_FLOATS             // 1728 f32: dw_w transposed [k][c]
#define WS_CMBB   (WS_DWT + 1728)       // 27648 bf16: heads weights [r][c]
#define WS_OUTB   (WS_CMBB + 13824)     // 4096 bf16: out_w native [j][c]
#define WS_INB    (WS_OUTB + 2048)      // 4096 bf16: in_w native [j][c]

typedef short  bf16x8 __attribute__((ext_vector_type(8)));
typedef float  f32x4  __attribute__((ext_vector_type(4)));

__device__ __forceinline__ unsigned short f2bf(float x) {
    unsigned u = __builtin_bit_cast(unsigned, x);
    u += 0x7fff + ((u >> 16) & 1);          // round-to-nearest-even
    return (unsigned short)(u >> 16);
}
__device__ __forceinline__ float bf2f(unsigned short v) {
    return __builtin_bit_cast(float, ((unsigned)v) << 16);
}
__device__ __forceinline__ bf16x8 pack8(float4 a, float4 b) {
    bf16x8 r;
    r[0] = (short)f2bf(a.x); r[1] = (short)f2bf(a.y);
    r[2] = (short)f2bf(a.z); r[3] = (short)f2bf(a.w);
    r[4] = (short)f2bf(b.x); r[5] = (short)f2bf(b.y);
    r[6] = (short)f2bf(b.z); r[7] = (short)f2bf(b.w);
    return r;
}

// ---------------------------------------------------------------------------
// Setup: zero xp (border ring stays zero) + build bf16/transposed weights.
// 2601 blocks x 256 covers XP_FLOATS/4 float4 zeros.
// ---------------------------------------------------------------------------
__global__ __launch_bounds__(256) void setup(
        const float* __restrict__ in_w,  const float* __restrict__ out_w,
        const float* __restrict__ off_w, const float* __restrict__ mask_w,
        const float* __restrict__ dw_w,  float* __restrict__ ws) {
    int t = blockIdx.x * 256 + threadIdx.x;
    if (t < XP_FLOATS / 4)
        ((float4*)ws)[t] = make_float4(0.f, 0.f, 0.f, 0.f);
    if (t < 1728) {
        int k = t >> 6, c = t & 63;
        ws[WS_DWT + t] = dw_w[c * 27 + k];
    }
    if (t < 27648) {
        unsigned short* cmbB = (unsigned short*)(ws + WS_CMBB);
        cmbB[t] = f2bf(t < 20736 ? off_w[t] : mask_w[t - 20736]);
    }
    if (t < 4096) {
        ((unsigned short*)(ws + WS_OUTB))[t] = f2bf(out_w[t]);
        ((unsigned short*)(ws + WS_INB))[t]  = f2bf(in_w[t]);
    }
}

// ---------------------------------------------------------------------------
// Value projection via MFMA: 64 voxels / block (4 waves x 16 voxels).
// A[m=vox][k=ch] = input (bf16), B[k=ch][n=j] = in_w[j][ch] (bf16), fp32 out.
// ---------------------------------------------------------------------------
__global__ __launch_bounds__(256) void value_proj(
        const float* __restrict__ inp,
        const float* __restrict__ ws_ro,
        const float* __restrict__ in_b,
        float* __restrict__ xp) {
    const unsigned short* inB = (const unsigned short*)(ws_ro + WS_INB);
    int u = threadIdx.x >> 6, lane = threadIdx.x & 63;
    int nid = lane & 15, quad = lane >> 4;
    int v0 = blockIdx.x * 64 + u * 16;

    const float* arow = inp + (size_t)(v0 + nid) * 64 + quad * 8;
    float4 f00 = *(const float4*)arow;
    float4 f01 = *(const float4*)(arow + 4);
    float4 f10 = *(const float4*)(arow + 32);
    float4 f11 = *(const float4*)(arow + 36);
    bf16x8 a0 = pack8(f00, f01);
    bf16x8 a1 = pack8(f10, f11);

    #pragma unroll
    for (int nt = 0; nt < 4; ++nt) {
        int j = nt * 16 + nid;
        bf16x8 b0 = *(const bf16x8*)&inB[j * 64 + quad * 8];
        bf16x8 b1 = *(const bf16x8*)&inB[j * 64 + quad * 8 + 32];
        f32x4 acc = {0.f, 0.f, 0.f, 0.f};
        acc = __builtin_amdgcn_mfma_f32_16x16x32_bf16(a0, b0, acc, 0, 0, 0);
        acc = __builtin_amdgcn_mfma_f32_16x16x32_bf16(a1, b1, acc, 0, 0, 0);
        float bias = in_b[j];
        #pragma unroll
        for (int k = 0; k < 4; ++k) {
            int vox = v0 + quad * 4 + k;
            int w = vox & 31, h = (vox >> 5) & 31, d = (vox >> 10) & 15, n = vox >> 14;
            xp[((((size_t)n * DIN + d + 1) * HIN + h + 1) * WIN + w + 1) * 64 + j] = acc[k] + bias;
        }
    }
}

// ---------------------------------------------------------------------------
// Fused main, 16 voxels / block (4 waves).
// ---------------------------------------------------------------------------
__global__ __launch_bounds__(256, 6) void dcn_main(
        const float* __restrict__ inp,
        const float* __restrict__ dw_b,
        const float* __restrict__ ln_g,  const float* __restrict__ ln_b,
        const float* __restrict__ off_b, const float* __restrict__ mask_b,
        const float* __restrict__ ws_ro,
        const float* __restrict__ out_b,
        float* __restrict__ out) {
    const float* xp   = ws_ro;
    const float* dwT  = ws_ro + WS_DWT;
    const unsigned short* cmbB = (const unsigned short*)(ws_ro + WS_CMBB);
    const unsigned short* outB = (const unsigned short*)(ws_ro + WS_OUTB);

    __shared__ __align__(16) unsigned short s_a[16 * 64];   // x1 bf16 [vox][ch]
    __shared__ unsigned short s_om[16 * SOMSTR];            // bf16 logits [vox][432]
    __shared__ __align__(16) unsigned short s_vb[16 * 64];  // sampled vals bf16

    int t = threadIdx.x;
    int u = t >> 6, lane = t & 63;
    int nid = lane & 15, quad = lane >> 4;
    int vox0 = blockIdx.x * 16;
    int w0 = vox0 & 31;
    int h0 = (vox0 >> 5) & 31;
    int d0 = (vox0 >> 10) & 15;
    int n  = vox0 >> 14;

    // ---- S1: depthwise conv (w-register-reuse) + LN + GELU
    {
        int c = lane;
        float dwb = dw_b[c];
        float acc[4] = {dwb, dwb, dwb, dwb};
        int wbase = w0 + u * 4;                 // wave's voxels: wbase..wbase+3
        #pragma unroll
        for (int kd = 0; kd < 3; ++kd) {
            int dz = d0 + kd - 1;
            if ((unsigned)dz >= DD) continue;
            #pragma unroll
            for (int kh = 0; kh < 3; ++kh) {
                int hy = h0 + kh - 1;
                if ((unsigned)hy >= HH) continue;
                const float* rowp = inp + ((((size_t)n * DD + dz) * HH + hy) * WW) * 64 + c;
                float cv[6];
                #pragma unroll
                for (int j = 0; j < 6; ++j) {
                    int wx = wbase - 1 + j;
                    cv[j] = ((unsigned)wx < WW) ? rowp[(size_t)wx * 64] : 0.f;
                }
                float wt0 = dwT[(kd * 9 + kh * 3 + 0) * 64 + c];
                float wt1 = dwT[(kd * 9 + kh * 3 + 1) * 64 + c];
                float wt2 = dwT[(kd * 9 + kh * 3 + 2) * 64 + c];
                #pragma unroll
                for (int i = 0; i < 4; ++i) {
                    acc[i] = fmaf(cv[i],     wt0, acc[i]);
                    acc[i] = fmaf(cv[i + 1], wt1, acc[i]);
                    acc[i] = fmaf(cv[i + 2], wt2, acc[i]);
                }
            }
        }
        #pragma unroll
        for (int i = 0; i < 4; ++i) {
            float a = acc[i];
            float s = a, ss = a * a;
            #pragma unroll
            for (int m = 1; m < 64; m <<= 1) {
                s  += __shfl_xor(s,  m, 64);
                ss += __shfl_xor(ss, m, 64);
            }
            float mu  = s * (1.f / 64.f);
            float var = ss * (1.f / 64.f) - mu * mu;
            float x1 = (a - mu) * rsqrtf(var + 1e-6f) * ln_g[c] + ln_b[c];
            x1 = 0.5f * x1 * (1.f + erff(x1 * 0.70710678118654752f));
            s_a[(u * 4 + i) * 64 + c] = f2bf(x1);
        }
    }
    __syncthreads();

    // ---- S2: heads (432 rows) via MFMA 16x16x32 bf16, 16 live A rows
    {
        bf16x8 a0 = *(const bf16x8*)&s_a[nid * 64 + quad * 8];
        bf16x8 a1 = *(const bf16x8*)&s_a[nid * 64 + quad * 8 + 32];
        for (int tl = u; tl < 27; tl += 4) {
            int r = tl * 16 + nid;
            bf16x8 b0 = *(const bf16x8*)&cmbB[r * 64 + quad * 8];
            bf16x8 b1 = *(const bf16x8*)&cmbB[r * 64 + quad * 8 + 32];
            f32x4 acc = {0.f, 0.f, 0.f, 0.f};
            acc = __builtin_amdgcn_mfma_f32_16x16x32_bf16(a0, b0, acc, 0, 0, 0);
            acc = __builtin_amdgcn_mfma_f32_16x16x32_bf16(a1, b1, acc, 0, 0, 0);
            float bias = (r < 324) ? off_b[r] : mask_b[r - 324];
            #pragma unroll
            for (int k = 0; k < 4; ++k)
                s_om[(quad * 4 + k) * SOMSTR + r] = f2bf(acc[k] + bias);
        }
    }
    __syncthreads();

    // ---- S3: softmax; quad (4 threads) per (vox, group)
    {
        int pair = t >> 2, l = t & 3;
        int vb = pair >> 2, g = pair & 3;
        unsigned short* m = &s_om[vb * SOMSTR + 324 + g * 27];
        float e[7];
        float mx = -1e30f;
        #pragma unroll
        for (int j = 0; j < 7; ++j) {
            int p = l + 4 * j;
            float v = (p < 27) ? bf2f(m[p]) : -1e30f;
            e[j] = v;
            mx = fmaxf(mx, v);
        }
        mx = fmaxf(mx, __shfl_xor(mx, 1, 64));
        mx = fmaxf(mx, __shfl_xor(mx, 2, 64));
        float sm = 0.f;
        #pragma unroll
        for (int j = 0; j < 7; ++j) {
            int p = l + 4 * j;
            e[j] = (p < 27) ? expf(e[j] - mx) : 0.f;
            sm += e[j];
        }
        sm += __shfl_xor(sm, 1, 64);
        sm += __shfl_xor(sm, 2, 64);
        float inv = 1.f / sm;
        #pragma unroll
        for (int j = 0; j < 7; ++j) {
            int p = l + 4 * j;
            if (p < 27) m[p] = f2bf(e[j] * inv);
        }
    }
    __syncthreads();

    // ---- S4: gather. wave u = group u; lane: vox vb=lane>>2, chquad cq=lane&3
    {
        int vb = lane >> 2, cq = lane & 3;
        int wv = w0 + vb;
        const unsigned short* om = &s_om[vb * SOMSTR];
        const float* xpn = xp + (size_t)n * (DIN * HIN * WIN * 64) + u * 16 + cq * 4;
        float4 acc = make_float4(0.f, 0.f, 0.f, 0.f);
        int p = 0;
        #pragma unroll
        for (int ix = 0; ix < 3; ++ix)
        #pragma unroll
        for (int iy = 0; iy < 3; ++iy)
        #pragma unroll
        for (int iz = 0; iz < 3; ++iz, ++p) {
            int rb = (u * 27 + p) * 3;
            float ox = bf2f(om[rb + 0]), oy = bf2f(om[rb + 1]), oz = bf2f(om[rb + 2]);
            float msk = bf2f(om[324 + u * 27 + p]);
            float px = (float)(wv + ix) + ox;
            float py = (float)(h0 + iy) + oy;
            float pz = (float)(d0 + iz) + oz;
            float fx0 = floorf(px); int x0 = (int)fx0; float fx = px - fx0;
            float fy0 = floorf(py); int y0 = (int)fy0; float fy = py - fy0;
            float fz0 = floorf(pz); int z0 = (int)fz0; float fz = pz - fz0;
            float wx0 = ((unsigned)x0       < WIN) ? (1.f - fx) : 0.f;
            float wx1 = ((unsigned)(x0 + 1) < WIN) ? fx         : 0.f;
            float wy0 = ((unsigned)y0       < HIN) ? (1.f - fy) : 0.f;
            float wy1 = ((unsigned)(y0 + 1) < HIN) ? fy         : 0.f;
            float wz0 = ((unsigned)z0       < DIN) ? (1.f - fz) : 0.f;
            float wz1 = ((unsigned)(z0 + 1) < DIN) ? fz         : 0.f;
            wz0 *= msk; wz1 *= msk;
            int x0c = min(max(x0, 0), WIN - 1), x1c = min(max(x0 + 1, 0), WIN - 1);
            int y0c = min(max(y0, 0), HIN - 1), y1c = min(max(y0 + 1, 0), HIN - 1);
            int z0c = min(max(z0, 0), DIN - 1), z1c = min(max(z0 + 1, 0), DIN - 1);
            int zb0 = z0c * (HIN * WIN), zb1 = z1c * (HIN * WIN);
            int yb0 = y0c * WIN,         yb1 = y1c * WIN;
            int r00 = (zb0 + yb0) << 6, r01 = (zb0 + yb1) << 6;
            int r10 = (zb1 + yb0) << 6, r11 = (zb1 + yb1) << 6;
            int xs0 = x0c << 6, xs1 = x1c << 6;
            float4 v000 = *(const float4*)(xpn + r00 + xs0);
            float4 v001 = *(const float4*)(xpn + r00 + xs1);
            float4 v010 = *(const float4*)(xpn + r01 + xs0);
            float4 v011 = *(const float4*)(xpn + r01 + xs1);
            float4 v100 = *(const float4*)(xpn + r10 + xs0);
            float4 v101 = *(const float4*)(xpn + r10 + xs1);
            float4 v110 = *(const float4*)(xpn + r11 + xs0);
            float4 v111 = *(const float4*)(xpn + r11 + xs1);
            float wzy00 = wz0 * wy0, wzy01 = wz0 * wy1;
            float wzy10 = wz1 * wy0, wzy11 = wz1 * wy1;
            float w000 = wzy00 * wx0, w001 = wzy00 * wx1;
            float w010 = wzy01 * wx0, w011 = wzy01 * wx1;
            float w100 = wzy10 * wx0, w101 = wzy10 * wx1;
            float w110 = wzy11 * wx0, w111 = wzy11 * wx1;
            #define TAP(W, V) \
                acc.x = fmaf(W, V.x, acc.x); acc.y = fmaf(W, V.y, acc.y); \
                acc.z = fmaf(W, V.z, acc.z); acc.w = fmaf(W, V.w, acc.w);
            TAP(w000, v000) TAP(w001, v001) TAP(w010, v010) TAP(w011, v011)
            TAP(w100, v100) TAP(w101, v101) TAP(w110, v110) TAP(w111, v111)
            #undef TAP
        }
        unsigned lo = (unsigned)f2bf(acc.x) | ((unsigned)f2bf(acc.y) << 16);
        unsigned hi = (unsigned)f2bf(acc.z) | ((unsigned)f2bf(acc.w) << 16);
        *(uint2*)&s_vb[vb * 64 + u * 16 + cq * 4] = make_uint2(lo, hi);
    }
    __syncthreads();

    // ---- S5: output projection via MFMA; wave u -> out channels 16u..16u+15
    {
        bf16x8 a0 = *(const bf16x8*)&s_vb[nid * 64 + quad * 8];
        bf16x8 a1 = *(const bf16x8*)&s_vb[nid * 64 + quad * 8 + 32];
        bf16x8 b0 = *(const bf16x8*)&outB[(u * 16 + nid) * 64 + quad * 8];
        bf16x8 b1 = *(const bf16x8*)&outB[(u * 16 + nid) * 64 + quad * 8 + 32];
        f32x4 acc = {0.f, 0.f, 0.f, 0.f};
        acc = __builtin_amdgcn_mfma_f32_16x16x32_bf16(a0, b0, acc, 0, 0, 0);
        acc = __builtin_amdgcn_mfma_f32_16x16x32_bf16(a1, b1, acc, 0, 0, 0);
        float ob = out_b[u * 16 + nid];
        #pragma unroll
        for (int k = 0; k < 4; ++k)
            out[(size_t)(vox0 + quad * 4 + k) * 64 + u * 16 + nid] = acc[k] + ob;
    }
}

extern "C" void kernel_launch(void* const* d_in, const int* in_sizes, int n_in,
                              void* d_out, int out_size, void* d_ws, size_t ws_size,
                              hipStream_t stream) {
    const float* inp    = (const float*)d_in[0];
    const float* dw_w   = (const float*)d_in[1];
    const float* dw_b   = (const float*)d_in[2];
    const float* ln_g   = (const float*)d_in[3];
    const float* ln_b   = (const float*)d_in[4];
    const float* off_w  = (const float*)d_in[5];
    const float* off_b  = (const float*)d_in[6];
    const float* mask_w = (const float*)d_in[7];
    const float* mask_b = (const float*)d_in[8];
    const float* in_w   = (const float*)d_in[9];
    const float* in_b   = (const float*)d_in[10];
    const float* out_w  = (const float*)d_in[11];
    const float* out_b  = (const float*)d_in[12];

    float* ws = (float*)d_ws;

    setup<<<2601, 256, 0, stream>>>(in_w, out_w, off_w, mask_w, dw_w, ws);
    value_proj<<<NVOX / 64, 256, 0, stream>>>(inp, ws, in_b, ws);
    dcn_main<<<NVOX / 16, 256, 0, stream>>>(inp, dw_b, ln_g, ln_b,
                                            off_b, mask_b, ws, out_b,
                                            (float*)d_out);
}

// Round 8
// 155.658 us; speedup vs baseline: 2.7582x; 1.3512x over previous
//
#include <hip/hip_runtime.h>
#include <math.h>

// Round 7: identical to round 6 (two "container failed twice" results were
// diagnosed as broker-side; source audited clean — see session journal).

#define NN 2
#define DD 16
#define HH 32
#define WW 32
#define DIN 18
#define HIN 34
#define WIN 34
#define NVOX 32768
#define NPAD (NN*DIN*HIN*WIN)    // 41616
#define PLANE (DIN*HIN*WIN)      // 20808
#define ROWS 432                 // 324 offset + 108 mask rows
#define SOMSTR 436               // s_om stride (bf16), conflict-free

// ws float offsets:
#define WS_XPG     16                        // bf16 value tensor [g][n][z][y][x][16ch], 64B pads
#define XPG_FLOATS (NPAD*32)                 // 1,331,712 floats = NPAD*64 bf16
#define WS_DWT     (WS_XPG + XPG_FLOATS + 16)   // 1728 f32: dw_w transposed [k][c]
#define WS_CMBB    (WS_DWT + 1728)           // 27648 bf16: heads weights [r][c]
#define WS_OUTB    (WS_CMBB + 13824)         // 4096 bf16: out_w native [j][c]
#define WS_INB     (WS_OUTB + 2048)          // 4096 bf16: in_w native [j][c]
#define ZERO_F4    ((16 + XPG_FLOATS + 16) / 4)   // 332,936 float4 zeros

typedef short  bf16x8 __attribute__((ext_vector_type(8)));
typedef float  f32x4  __attribute__((ext_vector_type(4)));

__device__ __forceinline__ unsigned short f2bf(float x) {
    unsigned u = __builtin_bit_cast(unsigned, x);
    u += 0x7fff + ((u >> 16) & 1);
    return (unsigned short)(u >> 16);
}
__device__ __forceinline__ float bf2f(unsigned short v) {
    return __builtin_bit_cast(float, ((unsigned)v) << 16);
}
__device__ __forceinline__ float bflo(unsigned u) {
    return __builtin_bit_cast(float, u << 16);
}
__device__ __forceinline__ float bfhi(unsigned u) {
    return __builtin_bit_cast(float, u & 0xffff0000u);
}
__device__ __forceinline__ bf16x8 pack8(float4 a, float4 b) {
    bf16x8 r;
    r[0] = (short)f2bf(a.x); r[1] = (short)f2bf(a.y);
    r[2] = (short)f2bf(a.z); r[3] = (short)f2bf(a.w);
    r[4] = (short)f2bf(b.x); r[5] = (short)f2bf(b.y);
    r[6] = (short)f2bf(b.z); r[7] = (short)f2bf(b.w);
    return r;
}

// ---------------------------------------------------------------------------
// Setup: zero xpg (border + pads) and build weight copies.
// ---------------------------------------------------------------------------
__global__ __launch_bounds__(256) void setup(
        const float* __restrict__ in_w,  const float* __restrict__ out_w,
        const float* __restrict__ off_w, const float* __restrict__ mask_w,
        const float* __restrict__ dw_w,  float* __restrict__ ws) {
    int t = blockIdx.x * 256 + threadIdx.x;
    if (t < ZERO_F4)
        ((float4*)ws)[t] = make_float4(0.f, 0.f, 0.f, 0.f);
    if (t < 1728) {
        int k = t >> 6, c = t & 63;
        ws[WS_DWT + t] = dw_w[c * 27 + k];
    }
    if (t < 27648) {
        unsigned short* cmbB = (unsigned short*)(ws + WS_CMBB);
        cmbB[t] = f2bf(t < 20736 ? off_w[t] : mask_w[t - 20736]);
    }
    if (t < 4096) {
        ((unsigned short*)(ws + WS_OUTB))[t] = f2bf(out_w[t]);
        ((unsigned short*)(ws + WS_INB))[t]  = f2bf(in_w[t]);
    }
}

// ---------------------------------------------------------------------------
// Value projection via MFMA -> bf16 group-major xpg.
// A = in_w rows (m=j), B = input (n=vox); D[j][vox]: lane nid = voxel,
// regs = 4 consecutive channels -> packed 8B stores into [g][...][x][16ch].
// ---------------------------------------------------------------------------
__global__ __launch_bounds__(256) void value_proj(
        const float* __restrict__ inp,
        const float* __restrict__ ws_ro,
        const float* __restrict__ in_b,
        float* __restrict__ ws_out) {
    const unsigned short* inB = (const unsigned short*)(ws_ro + WS_INB);
    unsigned short* xpg = (unsigned short*)(ws_out + WS_XPG);
    int hw = blockIdx.x;
    int L = (hw & 7) * 64 + (hw >> 3);        // XCD-contiguous remap (512 blocks)
    int u = threadIdx.x >> 6, lane = threadIdx.x & 63;
    int nid = lane & 15, quad = lane >> 4;
    int v0 = L * 64 + u * 16;

    int vx = v0 + nid;
    int w = vx & 31, h = (vx >> 5) & 31, d = (vx >> 10) & 15, n = vx >> 14;
    int pvox = ((n * DIN + d + 1) * HIN + h + 1) * WIN + (w + 1);

    const float* ip = inp + (size_t)vx * 64;
    bf16x8 b0 = pack8(*(const float4*)(ip + quad * 8),
                      *(const float4*)(ip + quad * 8 + 4));
    bf16x8 b1 = pack8(*(const float4*)(ip + quad * 8 + 32),
                      *(const float4*)(ip + quad * 8 + 36));

    #pragma unroll
    for (int t = 0; t < 4; ++t) {
        bf16x8 a0 = *(const bf16x8*)&inB[(16 * t + nid) * 64 + quad * 8];
        bf16x8 a1 = *(const bf16x8*)&inB[(16 * t + nid) * 64 + quad * 8 + 32];
        f32x4 acc = {0.f, 0.f, 0.f, 0.f};
        acc = __builtin_amdgcn_mfma_f32_16x16x32_bf16(a0, b0, acc, 0, 0, 0);
        acc = __builtin_amdgcn_mfma_f32_16x16x32_bf16(a1, b1, acc, 0, 0, 0);
        // lane holds D rows j = 16t + 4*quad + k, col = voxel vx
        float bs0 = in_b[16 * t + 4 * quad + 0];
        float bs1 = in_b[16 * t + 4 * quad + 1];
        float bs2 = in_b[16 * t + 4 * quad + 2];
        float bs3 = in_b[16 * t + 4 * quad + 3];
        unsigned d0 = (unsigned)f2bf(acc[0] + bs0) | ((unsigned)f2bf(acc[1] + bs1) << 16);
        unsigned d1 = (unsigned)f2bf(acc[2] + bs2) | ((unsigned)f2bf(acc[3] + bs3) << 16);
        *(uint2*)&xpg[((size_t)t * NPAD + pvox) * 16 + 4 * quad] = make_uint2(d0, d1);
    }
}

// ---------------------------------------------------------------------------
// Fused main, 16 voxels / block (4 waves).
// ---------------------------------------------------------------------------
__global__ __launch_bounds__(256, 6) void dcn_main(
        const float* __restrict__ inp,
        const float* __restrict__ dw_b,
        const float* __restrict__ ln_g,  const float* __restrict__ ln_b,
        const float* __restrict__ off_b, const float* __restrict__ mask_b,
        const float* __restrict__ ws_ro,
        const float* __restrict__ out_b,
        float* __restrict__ out) {
    const unsigned short* xpg  = (const unsigned short*)(ws_ro + WS_XPG);
    const float* dwT  = ws_ro + WS_DWT;
    const unsigned short* cmbB = (const unsigned short*)(ws_ro + WS_CMBB);
    const unsigned short* outB = (const unsigned short*)(ws_ro + WS_OUTB);

    __shared__ __align__(16) unsigned short s_a[16 * 64];   // x1 bf16 [vox][ch]
    __shared__ unsigned short s_om[16 * SOMSTR];            // bf16 logits [vox][432]
    __shared__ __align__(16) unsigned short s_vb[16 * 64];  // sampled vals bf16

    int t = threadIdx.x;
    int u = t >> 6, lane = t & 63;
    int nid = lane & 15, quad = lane >> 4;
    int hw = blockIdx.x;
    int L = (hw & 7) * 256 + (hw >> 3);       // XCD-contiguous remap (2048 blocks)
    int vox0 = L * 16;
    int w0 = vox0 & 31;
    int h0 = (vox0 >> 5) & 31;
    int d0 = (vox0 >> 10) & 15;
    int n  = vox0 >> 14;

    // ---- S1: depthwise conv (w-register-reuse) + LN + GELU
    {
        int c = lane;
        float dwb = dw_b[c];
        float acc[4] = {dwb, dwb, dwb, dwb};
        int wbase = w0 + u * 4;
        #pragma unroll
        for (int kd = 0; kd < 3; ++kd) {
            int dz = d0 + kd - 1;
            if ((unsigned)dz >= DD) continue;
            #pragma unroll
            for (int kh = 0; kh < 3; ++kh) {
                int hy = h0 + kh - 1;
                if ((unsigned)hy >= HH) continue;
                const float* rowp = inp + ((((size_t)n * DD + dz) * HH + hy) * WW) * 64 + c;
                float cv[6];
                #pragma unroll
                for (int j = 0; j < 6; ++j) {
                    int wx = wbase - 1 + j;
                    cv[j] = ((unsigned)wx < WW) ? rowp[(size_t)wx * 64] : 0.f;
                }
                float wt0 = dwT[(kd * 9 + kh * 3 + 0) * 64 + c];
                float wt1 = dwT[(kd * 9 + kh * 3 + 1) * 64 + c];
                float wt2 = dwT[(kd * 9 + kh * 3 + 2) * 64 + c];
                #pragma unroll
                for (int i = 0; i < 4; ++i) {
                    acc[i] = fmaf(cv[i],     wt0, acc[i]);
                    acc[i] = fmaf(cv[i + 1], wt1, acc[i]);
                    acc[i] = fmaf(cv[i + 2], wt2, acc[i]);
                }
            }
        }
        #pragma unroll
        for (int i = 0; i < 4; ++i) {
            float a = acc[i];
            float s = a, ss = a * a;
            #pragma unroll
            for (int m = 1; m < 64; m <<= 1) {
                s  += __shfl_xor(s,  m, 64);
                ss += __shfl_xor(ss, m, 64);
            }
            float mu  = s * (1.f / 64.f);
            float var = ss * (1.f / 64.f) - mu * mu;
            float x1 = (a - mu) * rsqrtf(var + 1e-6f) * ln_g[c] + ln_b[c];
            x1 = 0.5f * x1 * (1.f + erff(x1 * 0.70710678118654752f));
            s_a[(u * 4 + i) * 64 + c] = f2bf(x1);
        }
    }
    __syncthreads();

    // ---- S2: heads (432 rows) via MFMA 16x16x32 bf16
    {
        bf16x8 a0 = *(const bf16x8*)&s_a[nid * 64 + quad * 8];
        bf16x8 a1 = *(const bf16x8*)&s_a[nid * 64 + quad * 8 + 32];
        for (int tl = u; tl < 27; tl += 4) {
            int r = tl * 16 + nid;
            bf16x8 b0 = *(const bf16x8*)&cmbB[r * 64 + quad * 8];
            bf16x8 b1 = *(const bf16x8*)&cmbB[r * 64 + quad * 8 + 32];
            f32x4 acc = {0.f, 0.f, 0.f, 0.f};
            acc = __builtin_amdgcn_mfma_f32_16x16x32_bf16(a0, b0, acc, 0, 0, 0);
            acc = __builtin_amdgcn_mfma_f32_16x16x32_bf16(a1, b1, acc, 0, 0, 0);
            float bias = (r < 324) ? off_b[r] : mask_b[r - 324];
            #pragma unroll
            for (int k = 0; k < 4; ++k)
                s_om[(quad * 4 + k) * SOMSTR + r] = f2bf(acc[k] + bias);
        }
    }
    __syncthreads();

    // ---- S3: softmax; quad (4 threads) per (vox, group)
    {
        int pair = t >> 2, l = t & 3;
        int vb = pair >> 2, g = pair & 3;
        unsigned short* m = &s_om[vb * SOMSTR + 324 + g * 27];
        float e[7];
        float mx = -1e30f;
        #pragma unroll
        for (int j = 0; j < 7; ++j) {
            int p = l + 4 * j;
            float v = (p < 27) ? bf2f(m[p]) : -1e30f;
            e[j] = v;
            mx = fmaxf(mx, v);
        }
        mx = fmaxf(mx, __shfl_xor(mx, 1, 64));
        mx = fmaxf(mx, __shfl_xor(mx, 2, 64));
        float sm = 0.f;
        #pragma unroll
        for (int j = 0; j < 7; ++j) {
            int p = l + 4 * j;
            e[j] = (p < 27) ? expf(e[j] - mx) : 0.f;
            sm += e[j];
        }
        sm += __shfl_xor(sm, 1, 64);
        sm += __shfl_xor(sm, 2, 64);
        float inv = 1.f / sm;
        #pragma unroll
        for (int j = 0; j < 7; ++j) {
            int p = l + 4 * j;
            if (p < 27) m[p] = f2bf(e[j] * inv);
        }
    }
    __syncthreads();

    // ---- S4: gather from bf16 group-major xpg.
    // wave u = group u; lane = (vb = lane>>2, q = lane&3);
    // q = xhalf*2 + chalf: lane loads 8 ch (16B) of x-tap xhalf.
    {
        int vb = lane >> 2, q = lane & 3;
        int chalf = q & 1, xhalf = q >> 1;
        int qo = q * 8;                         // short offset within 64B pair-segment
        int wv = w0 + vb;
        const unsigned short* om = &s_om[vb * SOMSTR];
        const unsigned short* xg = xpg + ((size_t)u * NPAD + (size_t)n * PLANE) * 16;
        float acc[8] = {0.f, 0.f, 0.f, 0.f, 0.f, 0.f, 0.f, 0.f};
        int p = 0;
        #pragma unroll
        for (int ix = 0; ix < 3; ++ix)
        #pragma unroll
        for (int iy = 0; iy < 3; ++iy)
        #pragma unroll
        for (int iz = 0; iz < 3; ++iz, ++p) {
            int rb = (u * 27 + p) * 3;
            float ox = bf2f(om[rb + 0]), oy = bf2f(om[rb + 1]), oz = bf2f(om[rb + 2]);
            float msk = bf2f(om[324 + u * 27 + p]);
            float px = (float)(wv + ix) + ox;
            float py = (float)(h0 + iy) + oy;
            float pz = (float)(d0 + iz) + oz;
            float fx0 = floorf(px); int x0 = (int)fx0; float fx = px - fx0;
            float fy0 = floorf(py); int y0 = (int)fy0; float fy = py - fy0;
            float fz0 = floorf(pz); int z0 = (int)fz0; float fz = pz - fz0;
            float wx0 = ((unsigned)x0       < WIN) ? (1.f - fx) : 0.f;
            float wx1 = ((unsigned)(x0 + 1) < WIN) ? fx         : 0.f;
            float wy0 = ((unsigned)y0       < HIN) ? (1.f - fy) : 0.f;
            float wy1 = ((unsigned)(y0 + 1) < HIN) ? fy         : 0.f;
            float wz0 = ((unsigned)z0       < DIN) ? (1.f - fz) : 0.f;
            float wz1 = ((unsigned)(z0 + 1) < DIN) ? fz         : 0.f;
            wz0 *= msk; wz1 *= msk;
            int x0c = min(max(x0, -1), WIN - 1);         // pair-load base (pad-safe)
            int y0c = min(max(y0, 0), HIN - 1), y1c = min(max(y0 + 1, 0), HIN - 1);
            int z0c = min(max(z0, 0), DIN - 1), z1c = min(max(z0 + 1, 0), DIN - 1);
            int r00 = (z0c * HIN + y0c) * WIN + x0c;
            int r01 = (z0c * HIN + y1c) * WIN + x0c;
            int r10 = (z1c * HIN + y0c) * WIN + x0c;
            int r11 = (z1c * HIN + y1c) * WIN + x0c;
            uint4 t00 = *(const uint4*)(xg + r00 * 16 + qo);
            uint4 t01 = *(const uint4*)(xg + r01 * 16 + qo);
            uint4 t10 = *(const uint4*)(xg + r10 * 16 + qo);
            uint4 t11 = *(const uint4*)(xg + r11 * 16 + qo);
            float wxq = xhalf ? wx1 : wx0;
            float w00 = wxq * wz0 * wy0;
            float w01 = wxq * wz0 * wy1;
            float w10 = wxq * wz1 * wy0;
            float w11 = wxq * wz1 * wy1;
            #define ACC8(T, W) { float w_ = (W); \
                acc[0] = fmaf(w_, bflo(T.x), acc[0]); acc[1] = fmaf(w_, bfhi(T.x), acc[1]); \
                acc[2] = fmaf(w_, bflo(T.y), acc[2]); acc[3] = fmaf(w_, bfhi(T.y), acc[3]); \
                acc[4] = fmaf(w_, bflo(T.z), acc[4]); acc[5] = fmaf(w_, bfhi(T.z), acc[5]); \
                acc[6] = fmaf(w_, bflo(T.w), acc[6]); acc[7] = fmaf(w_, bfhi(T.w), acc[7]); }
            ACC8(t00, w00) ACC8(t01, w01) ACC8(t10, w10) ACC8(t11, w11)
            #undef ACC8
        }
        // combine the two x-halves (lanes q and q^2)
        #pragma unroll
        for (int i = 0; i < 8; ++i) acc[i] += __shfl_xor(acc[i], 2, 64);
        if (q < 2) {
            unsigned d0 = (unsigned)f2bf(acc[0]) | ((unsigned)f2bf(acc[1]) << 16);
            unsigned d1 = (unsigned)f2bf(acc[2]) | ((unsigned)f2bf(acc[3]) << 16);
            unsigned d2 = (unsigned)f2bf(acc[4]) | ((unsigned)f2bf(acc[5]) << 16);
            unsigned d3 = (unsigned)f2bf(acc[6]) | ((unsigned)f2bf(acc[7]) << 16);
            *(uint4*)&s_vb[vb * 64 + u * 16 + chalf * 8] = make_uint4(d0, d1, d2, d3);
        }
    }
    __syncthreads();

    // ---- S5: output projection via MFMA; wave u -> out channels 16u..16u+15
    {
        bf16x8 a0 = *(const bf16x8*)&s_vb[nid * 64 + quad * 8];
        bf16x8 a1 = *(const bf16x8*)&s_vb[nid * 64 + quad * 8 + 32];
        bf16x8 b0 = *(const bf16x8*)&outB[(u * 16 + nid) * 64 + quad * 8];
        bf16x8 b1 = *(const bf16x8*)&outB[(u * 16 + nid) * 64 + quad * 8 + 32];
        f32x4 acc = {0.f, 0.f, 0.f, 0.f};
        acc = __builtin_amdgcn_mfma_f32_16x16x32_bf16(a0, b0, acc, 0, 0, 0);
        acc = __builtin_amdgcn_mfma_f32_16x16x32_bf16(a1, b1, acc, 0, 0, 0);
        float ob = out_b[u * 16 + nid];
        #pragma unroll
        for (int k = 0; k < 4; ++k)
            out[(size_t)(vox0 + quad * 4 + k) * 64 + u * 16 + nid] = acc[k] + ob;
    }
}

extern "C" void kernel_launch(void* const* d_in, const int* in_sizes, int n_in,
                              void* d_out, int out_size, void* d_ws, size_t ws_size,
                              hipStream_t stream) {
    const float* inp    = (const float*)d_in[0];
    const float* dw_w   = (const float*)d_in[1];
    const float* dw_b   = (const float*)d_in[2];
    const float* ln_g   = (const float*)d_in[3];
    const float* ln_b   = (const float*)d_in[4];
    const float* off_w  = (const float*)d_in[5];
    const float* off_b  = (const float*)d_in[6];
    const float* mask_w = (const float*)d_in[7];
    const float* mask_b = (const float*)d_in[8];
    const float* in_w   = (const float*)d_in[9];
    const float* in_b   = (const float*)d_in[10];
    const float* out_w  = (const float*)d_in[11];
    const float* out_b  = (const float*)d_in[12];

    float* ws = (float*)d_ws;

    setup<<<1302, 256, 0, stream>>>(in_w, out_w, off_w, mask_w, dw_w, ws);
    value_proj<<<NVOX / 64, 256, 0, stream>>>(inp, ws, in_b, ws);
    dcn_main<<<NVOX / 16, 256, 0, stream>>>(inp, dw_b, ln_g, ln_b,
                                            off_b, mask_b, ws, out_b,
                                            (float*)d_out);
}